// Round 12
// baseline (416.723 us; speedup 1.0000x reference)
//
#include <hip/hip_runtime.h>
#include <cstdint>
#include <cstddef>

typedef _Float16 half8 __attribute__((ext_vector_type(8)));
typedef _Float16 half4 __attribute__((ext_vector_type(4)));
typedef float f32x4 __attribute__((ext_vector_type(4)));
typedef float f32x2 __attribute__((ext_vector_type(2)));
typedef int iv4 __attribute__((ext_vector_type(4)));

#define GAT_N 8192
#define GAT_F 256
#define GAT_NQ 8     // key slices of 1024
#define GAT_ALPHA 0.2f
#define GAT_LOG2E 1.4426950408889634f

// Monotone float->uint encoding for atomicMax over floats of any sign.
__device__ inline unsigned enc_f32(float x) {
    unsigned b = __float_as_uint(x);
    return (b & 0x80000000u) ? ~b : (b | 0x80000000u);
}
__device__ inline float dec_f32(unsigned u) {
    unsigned b = (u & 0x80000000u) ? (u ^ 0x80000000u) : ~u;
    return __uint_as_float(b);
}

// Compare+pack 8 adj int32s (two iv4) into an 8-bit edge mask.
__device__ inline unsigned pack8(iv4 v0, iv4 v1) {
    return (unsigned)(v0[0] > 0)        | ((unsigned)(v0[1] > 0) << 1)
         | ((unsigned)(v0[2] > 0) << 2) | ((unsigned)(v0[3] > 0) << 3)
         | ((unsigned)(v1[0] > 0) << 4) | ((unsigned)(v1[1] > 0) << 5)
         | ((unsigned)(v1[2] > 0) << 6) | ((unsigned)(v1[3] > 0) << 7);
}

// whT2 layout: 128 tiles (64 keys each) x [oct(8)][feat(256)][key&7(8)] fp16.
// addr(halves) = (key>>6)*16384 + ((key&63)>>3)*2048 + feat*8 + (key&7).
// This is EXACTLY the K3 LDS chunk order, so staging is a linear copy with
// unit-stride lanes (global_load_lds: per-lane global addr, implicit lane*16
// LDS dest).

// ---------------------------------------------------------------------------
// K0b: W -> fp16 transposed WT[n][k]; init encoded f2max.
// ---------------------------------------------------------------------------
__global__ __launch_bounds__(256) void gat_k0b_convert(
    const float* __restrict__ W, _Float16* __restrict__ WT,
    unsigned* __restrict__ f2mxEnc)
{
    const int g = blockIdx.x * 256 + threadIdx.x;
    if (g == 0) *f2mxEnc = 0u;                          // enc(-FLT_MAX)
    const int k = g >> 8, n = g & 255;
    WT[n * GAT_F + k] = (_Float16)W[g];
}

// ---------------------------------------------------------------------------
// K1: Wh = h @ W via fp16 MFMA. grid 512 x 256 thr: block = 16 rows (=16
// keys), wave wv = col-quarter (64 cols, 4 tiles). Cross-wave f1/f2 via LDS.
// Epilogue writes whT2 in TILED layout (key of K3 = row of Wh).
// R21: h loads NONTEMPORAL via ext-vector f32x4 (HIP float4 is rejected by
// the builtin). Read-once stream; keep L2 for WT/whT2.
// ---------------------------------------------------------------------------
__global__ __launch_bounds__(256, 2) void gat_k1_gemm(
    const float* __restrict__ h, const _Float16* __restrict__ WT,
    const float* __restrict__ a, _Float16* __restrict__ whT2,
    float* __restrict__ f1L, float* __restrict__ f2L,
    unsigned* __restrict__ f2mxEnc)
{
    __shared__ float sP1[4][16], sP2[4][16];
    const int wv = threadIdx.x >> 6;
    const int lane = threadIdx.x & 63;
    const int l15 = lane & 15;
    const int quad = lane >> 4;
    const int r0 = blockIdx.x * 16;

    f32x4 acc[4];
    #pragma unroll
    for (int t = 0; t < 4; ++t) { f32x4 z = {0.f,0.f,0.f,0.f}; acc[t] = z; }

    #pragma unroll
    for (int k0 = 0; k0 < GAT_F; k0 += 32) {
        const float* ap = h + (size_t)(r0 + l15) * GAT_F + k0 + quad * 8;
        const f32x4 a0 = __builtin_nontemporal_load(
            reinterpret_cast<const f32x4*>(ap));
        const f32x4 a1 = __builtin_nontemporal_load(
            reinterpret_cast<const f32x4*>(ap + 4));
        half8 af;
        af[0] = (_Float16)a0[0]; af[1] = (_Float16)a0[1];
        af[2] = (_Float16)a0[2]; af[3] = (_Float16)a0[3];
        af[4] = (_Float16)a1[0]; af[5] = (_Float16)a1[1];
        af[6] = (_Float16)a1[2]; af[7] = (_Float16)a1[3];
        #pragma unroll
        for (int t = 0; t < 4; ++t) {
            half8 bf = *reinterpret_cast<const half8*>(
                WT + (size_t)(wv * 64 + t * 16 + l15) * GAT_F + k0 + quad * 8);
            acc[t] = __builtin_amdgcn_mfma_f32_16x16x32_f16(af, bf, acc[t], 0, 0, 0);
        }
    }

    float p1[4] = {0.f,0.f,0.f,0.f}, p2[4] = {0.f,0.f,0.f,0.f};
    #pragma unroll
    for (int t = 0; t < 4; ++t) {
        float a1c = a[wv * 64 + t * 16 + l15];
        float a2c = a[GAT_F + wv * 64 + t * 16 + l15];
        #pragma unroll
        for (int r = 0; r < 4; ++r) {
            p1[r] = fmaf(acc[t][r], a1c, p1[r]);
            p2[r] = fmaf(acc[t][r], a2c, p2[r]);
        }
    }
    #pragma unroll
    for (int off = 1; off < 16; off <<= 1) {
        #pragma unroll
        for (int r = 0; r < 4; ++r) {
            p1[r] += __shfl_xor(p1[r], off);
            p2[r] += __shfl_xor(p2[r], off);
        }
    }
    if (l15 == 0) {
        #pragma unroll
        for (int r = 0; r < 4; ++r) {
            sP1[wv][quad * 4 + r] = p1[r];
            sP2[wv][quad * 4 + r] = p2[r];
        }
    }
    __syncthreads();
    if (threadIdx.x < 16) {
        const int row = threadIdx.x;
        const float s1 = (sP1[0][row] + sP1[1][row] + sP1[2][row] + sP1[3][row]) * GAT_LOG2E;
        const float s2 = (sP2[0][row] + sP2[1][row] + sP2[2][row] + sP2[3][row]) * GAT_LOG2E;
        f1L[r0 + row] = s1;
        f2L[r0 + row] = s2;
        float mx = s2;
        #pragma unroll
        for (int off = 1; off < 16; off <<= 1) mx = fmaxf(mx, __shfl_xor(mx, off));
        if (row == 0) atomicMax(f2mxEnc, enc_f32(mx));
    }

    // Tiled whT2 store (TEMPORAL: K3 re-reads it from L2). Keys r0+quad*4+r,
    // feat c: tile = r0>>6, oct = ((r0&63)>>3)+(quad>>1), key&7 = (quad&1)*4+r.
    const size_t tbase = (size_t)(r0 >> 6) * 16384
                       + (((r0 & 63) >> 3) + (quad >> 1)) * 2048
                       + (quad & 1) * 4;
    #pragma unroll
    for (int t = 0; t < 4; ++t) {
        const int c = wv * 64 + t * 16 + l15;
        half4 hv;
        #pragma unroll
        for (int r = 0; r < 4; ++r) hv[r] = (_Float16)acc[t][r];
        *reinterpret_cast<half4*>(whT2 + tbase + c * 8) = hv;
    }
}

// ---------------------------------------------------------------------------
// K3: fused masked softmax-numerator x V. R19 champion (415 us), UNCHANGED:
// R2 structure + nontemporal adj loads (the 268 MB one-shot stream no longer
// evicts the L2-resident whT2 staging source; stage global_load_lds hits L2
// at ~200 cy instead of missing to L3/HBM at 600-900 cy, and the per-step
// vmcnt(0) drain stops paying that latency 16x) + nontemporal Ph stores.
// Verified: 430 -> 415 us, bit-identical output.
// grid = 64 rb x 8 q = 512 blocks at (256,2).
// ---------------------------------------------------------------------------
__global__ __launch_bounds__(256, 2) void gat_k3_attn(
    const int* __restrict__ adj, const float* __restrict__ f1L,
    const float* __restrict__ f2L, const unsigned* __restrict__ f2mxEnc,
    const _Float16* __restrict__ whT2,
    _Float16* __restrict__ Ph,     // 8 slabs x 8192x256 fp16, permuted
    float* __restrict__ L)         // [8][8192]
{
    __shared__ __align__(16) _Float16 sB[2][16384];   // 2 x 32 KB (full 64-key tile)

    const int bx = blockIdx.x;
    const int q  = bx & 7;           // key slice 0..7
    const int rb = bx >> 3;          // row group 0..63
    const int wv = threadIdx.x >> 6;
    const int lane = threadIdx.x & 63;
    const int l15 = lane & 15;
    const int quad = lane >> 4;

    const int kq = q * 1024;
    const int r0 = rb * 128 + wv * 32;
    const int rA = r0 + l15;
    const int rB = rA + 16;

    const float fmxL = dec_f32(*f2mxEnc);
    const float f1A = f1L[rA];
    const float f1B = f1L[rB];
    const float sA = f1A + fmxL;
    const float sBv = f1B + fmxL;
    const float CA = fmaxf(sA, GAT_ALPHA * sA);
    const float CB = fmaxf(sBv, GAT_ALPHA * sBv);
    // exp2 arg = max(xa, a*xa) - C = max((f1-C)+f2j, (a*f1-C)+a*f2j)
    const float uA = f1A - CA, vA = GAT_ALPHA * f1A - CA;
    const float uB = f1B - CB, vB = GAT_ALPHA * f1B - CB;

    f32x4 acc[2][16];
    #pragma unroll
    for (int s = 0; s < 2; ++s)
        #pragma unroll
        for (int t = 0; t < 16; ++t) {
            f32x4 z = {0.f,0.f,0.f,0.f};
            acc[s][t] = z;
        }
    float d0 = 0.f, d1 = 0.f;

    // Raw adj tile pointers. Keys for (step,k2,j): step*64 + k2*32 + quad*8 + j.
    const int* aprA = adj + (size_t)rA * GAT_N + kq + quad * 8;
    const int* aprB = adj + (size_t)rB * GAT_N + kq + quad * 8;
    const float* f2q = f2L + kq + quad * 8;

    // 8 named iv4 regs (static indexing; runtime-indexed arrays spill).
    // NONTEMPORAL: one-shot stream, keep it out of L2 (protect whT2).
    iv4 xA0, xA1, xA2, xA3, xB0, xB1, xB2, xB3;
    #define ADJLOAD(s)                                                         \
        {                                                                      \
            const iv4* pa = reinterpret_cast<const iv4*>(aprA + (s) * 64);     \
            const iv4* pb = reinterpret_cast<const iv4*>(aprB + (s) * 64);     \
            xA0 = __builtin_nontemporal_load(pa);                              \
            xA1 = __builtin_nontemporal_load(pa + 1);                          \
            xA2 = __builtin_nontemporal_load(pa + 8);                          \
            xA3 = __builtin_nontemporal_load(pa + 9);                          \
            xB0 = __builtin_nontemporal_load(pb);                              \
            xB1 = __builtin_nontemporal_load(pb + 1);                          \
            xB2 = __builtin_nontemporal_load(pb + 8);                          \
            xB3 = __builtin_nontemporal_load(pb + 9);                          \
        }
    // bit (k2*8 + j) of mask <-> key step*64 + k2*32 + quad*8 + j
    #define ADJPACK(ma, mb)                                                    \
        {                                                                      \
            ma = pack8(xA0, xA1) | (pack8(xA2, xA3) << 8);                     \
            mb = pack8(xB0, xB1) | (pack8(xB2, xB3) << 8);                     \
        }

    // STAGE(buf, step): copy full 64-key tile (32 KB) from whT2. Pure linear
    // copy: wave wv covers halves [wv*4096, wv*4096+4096); instr i copies
    // 1 KB (64 lanes x 16 B, unit-stride). PER-LANE global addr = base +
    // lane*8 halves; LDS dest implicit lane*16.
    const _Float16* tile0 = whT2 + (size_t)(q * 16) * 16384 + (size_t)lane * 8;
    #define STAGE(buf, step)                                                   \
        {                                                                      \
            _Pragma("unroll")                                                  \
            for (int i = 0; i < 8; ++i) {                                      \
                const int off = wv * 4096 + i * 512;                           \
                const _Float16* gp = tile0 + (size_t)(step) * 16384 + off;     \
                _Float16* lp = &sB[buf][off];                                  \
                __builtin_amdgcn_global_load_lds(                              \
                    (const __attribute__((address_space(1))) void*)gp,         \
                    (__attribute__((address_space(3))) void*)lp, 16, 0, 0);    \
            }                                                                  \
        }

    ADJLOAD(0)
    float4 nfa = *reinterpret_cast<const float4*>(f2q);
    float4 nfb = *reinterpret_cast<const float4*>(f2q + 4);
    STAGE(0, 0)
    unsigned cmA, cmB;
    ADJPACK(cmA, cmB)                // waits step-0 adj loads (prologue only)
    unsigned nmA = 0, nmB = 0;
    __syncthreads();   // buf0 staged (barrier drains vmcnt)

    for (int step = 0; step < 16; ++step) {   // 64 keys per step
        const int cur = step & 1;
        if (step < 15) {
            ADJLOAD(step + 1)                 // issue early, pack at step end
            STAGE(1 - cur, step + 1)
        }

        #pragma unroll
        for (int k2 = 0; k2 < 2; ++k2) {    // sub = 32 keys (one MFMA K)
            const int u = step * 2 + k2;
            const float4 cfa = nfa, cfb = nfb;
            if (u < 31) {
                nfa = *reinterpret_cast<const float4*>(f2q + (u + 1) * 32);
                nfb = *reinterpret_cast<const float4*>(f2q + (u + 1) * 32 + 4);
            }
            const unsigned mA = (cmA >> (k2 * 8)) & 0xffu;
            const unsigned mB = (cmB >> (k2 * 8)) & 0xffu;
            const float f2v[8] = {cfa.x, cfa.y, cfa.z, cfa.w,
                                  cfb.x, cfb.y, cfb.z, cfb.w};
            float af2[8];
            #pragma unroll
            for (int j = 0; j < 8; ++j) af2[j] = GAT_ALPHA * f2v[j];

            half8 pA, pB;
            #pragma unroll
            for (int j = 0; j < 8; ++j) {
                float pa = __builtin_amdgcn_exp2f(fmaxf(uA + f2v[j], vA + af2[j]));
                pa = (mA & (1u << j)) ? pa : 0.f;
                d0 += pa;
                pA[j] = (_Float16)pa;
                float pb = __builtin_amdgcn_exp2f(fmaxf(uB + f2v[j], vB + af2[j]));
                pb = (mB & (1u << j)) ? pb : 0.f;
                d1 += pb;
                pB[j] = (_Float16)pb;
            }

            // chunk koct = k2*4+quad; halves = koct*2048 + feat*8 + key7
            const int lbase = (k2 * 4 + quad) * 2048 + l15 * 8;
            #pragma unroll
            for (int t = 0; t < 16; ++t) {
                half8 bf = *reinterpret_cast<const half8*>(
                    &sB[cur][lbase + t * 128]);
                acc[0][t] = __builtin_amdgcn_mfma_f32_16x16x32_f16(pA, bf, acc[0][t], 0, 0, 0);
                acc[1][t] = __builtin_amdgcn_mfma_f32_16x16x32_f16(pB, bf, acc[1][t], 0, 0, 0);
            }
        }
        if (step < 15) ADJPACK(nmA, nmB)      // loads landed under this step
        __syncthreads();   // drains stage(step+1) + this step's ds_reads
        cmA = nmA; cmB = nmB;
    }
    #undef STAGE
    #undef ADJLOAD
    #undef ADJPACK

    // Row denominators (one block per (rb,q) -> write unconditionally).
    d0 += __shfl_xor(d0, 16); d0 += __shfl_xor(d0, 32);
    d1 += __shfl_xor(d1, 16); d1 += __shfl_xor(d1, 32);
    if (lane < 16) {
        float* Lq = L + q * GAT_N;
        Lq[rA] = d0; Lq[rB] = d1;
    }

    // Coalesced permuted fp16 partial store; NONTEMPORAL (write-once stream,
    // read once by K4 -> keep out of L2).
    const int wid = rb * 4 + wv;                       // 0..255
    _Float16* Pq = Ph + ((size_t)q * 256 + wid) * 8192;
    #pragma unroll
    for (int s = 0; s < 2; ++s)
        #pragma unroll
        for (int t = 0; t < 16; ++t) {
            half4 hv;
            #pragma unroll
            for (int r = 0; r < 4; ++r) hv[r] = (_Float16)acc[s][t][r];
            __builtin_nontemporal_store(hv,
                reinterpret_cast<half4*>(Pq + (size_t)(((s * 16 + t) * 64 + lane) * 4)));
        }
}

// ---------------------------------------------------------------------------
// K4: un-permute + combine 8 fp16 partials, normalize, ELU, write out.
// R21: 16B loads (half8 = two adjacent half4 positions -> same 4 rows,
// adjacent cols), paired f32x2 stores (ext-vector: HIP float2 rejected by
// the nt builtin), NONTEMPORAL both ways (one-shot streams). 1024 blocks x
// 256 thr; accumulation order per output unchanged -> bit-identical.
// ---------------------------------------------------------------------------
__global__ __launch_bounds__(256) void gat_k4_final(
    const _Float16* __restrict__ Ph, const float* __restrict__ L,
    float* __restrict__ out)
{
    const int tid = threadIdx.x;
    const int wid = blockIdx.x >> 2;                   // 32-row chunk 0..255
    __shared__ float s_rl[32];
    if (tid < 32) {
        const int row = wid * 32 + tid;
        float s = 0.f;
        #pragma unroll
        for (int q = 0; q < GAT_NQ; ++q) s += L[q * GAT_N + row];
        s_rl[tid] = 1.0f / fmaxf(s, 1e-30f);
    }
    __syncthreads();

    const int pidx = (blockIdx.x & 3) * 256 + tid;     // pair idx in chunk 0..1023
    const int rem = pidx * 2;                          // even half4 position
    const int lane = rem & 63;                         // even lane
    const int st = rem >> 6;
    const int s = st >> 4, t = st & 15;
    const int l15 = lane & 15, quad = lane >> 4;       // l15 even <= 14
    const int lrow0 = s * 16 + quad * 4;               // local rows lrow0..+3
    const int col = t * 16 + l15;                      // pair covers col, col+1

    float a0[4] = {0.f, 0.f, 0.f, 0.f};
    float a1[4] = {0.f, 0.f, 0.f, 0.f};
    #pragma unroll
    for (int q = 0; q < GAT_NQ; ++q) {
        half8 v = __builtin_nontemporal_load(reinterpret_cast<const half8*>(
            Ph + ((size_t)q * 256 + wid) * 8192 + (size_t)rem * 4));
        #pragma unroll
        for (int r = 0; r < 4; ++r) {
            a0[r] += (float)v[r];
            a1[r] += (float)v[4 + r];
        }
    }
    #pragma unroll
    for (int r = 0; r < 4; ++r) {
        const float rl = s_rl[lrow0 + r];
        const float v0 = a0[r] * rl;
        const float v1 = a1[r] * rl;
        f32x2 o;
        o[0] = v0 > 0.f ? v0 : expm1f(v0);
        o[1] = v1 > 0.f ? v1 : expm1f(v1);
        __builtin_nontemporal_store(o, reinterpret_cast<f32x2*>(
            &out[(size_t)(wid * 32 + lrow0 + r) * GAT_F + col]));
    }
}

// ---------------------------------------------------------------------------
extern "C" void kernel_launch(void* const* d_in, const int* in_sizes, int n_in,
                              void* d_out, int out_size, void* d_ws, size_t ws_size,
                              hipStream_t stream)
{
    const float* h   = (const float*)d_in[0];
    const int*   adj = (const int*)d_in[1];
    // d_in[2] = cv_values: constant per softmax row -> cancels exactly; unused.
    const float* W   = (const float*)d_in[3];
    const float* a   = (const float*)d_in[4];
    float* out = (float*)d_out;
    char* ws = (char*)d_ws;

    const size_t SLAB = (size_t)GAT_N * GAT_F * 2;     // 4 MiB (fp16 matrix)

    size_t off = 0;
    _Float16* whT2 = (_Float16*)(ws + off); off += SLAB;           // 4 MiB tiled
    _Float16* Ph  = (_Float16*)(ws + off); off += GAT_NQ * SLAB;   // 32 MiB
    _Float16* WT  = (_Float16*)(ws + off); off += (size_t)GAT_F * GAT_F * 2;  // 128 KiB
    float* f1L = (float*)(ws + off); off += GAT_N * 4;
    float* f2L = (float*)(ws + off); off += GAT_N * 4;
    float* L   = (float*)(ws + off); off += GAT_NQ * GAT_N * 4;
    unsigned* f2mxEnc = (unsigned*)(ws + off); off += 256;

    gat_k0b_convert<<<256, 256, 0, stream>>>(W, WT, f2mxEnc);
    gat_k1_gemm<<<512, 256, 0, stream>>>(h, WT, a, whT2, f1L, f2L, f2mxEnc);
    gat_k3_attn<<<512, 256, 0, stream>>>(adj, f1L, f2L, f2mxEnc, whT2, Ph, L);
    gat_k4_final<<<1024, 256, 0, stream>>>(Ph, L, out);
}